// Round 1
// baseline (7111.581 us; speedup 1.0000x reference)
//
#include <hip/hip_runtime.h>

#define NN 100000
#define NE 1600000
#define BN_EPS 1e-5f

// ---------------- degree / dinv ----------------
__global__ void k_init_deg(float* __restrict__ deg) {
    int i = blockIdx.x * 256 + threadIdx.x;
    if (i < NN) deg[i] = 1.0f;
}

__global__ void k_count_deg(const int* __restrict__ dst, float* __restrict__ deg) {
    int e = blockIdx.x * 256 + threadIdx.x;
    if (e < NE) atomicAdd(&deg[dst[e]], 1.0f);
}

__global__ void k_dinv(float* __restrict__ deg) {
    int i = blockIdx.x * 256 + threadIdx.x;
    if (i < NN) deg[i] = rsqrtf(deg[i]);
}

// ---------------- GEMM: out[row,:] = (A[row,:] @ W) * dinv[row] ----------------
// W staged fully in LDS. One thread computes 4 consecutive output cols.
template <int K, int M>
__global__ __launch_bounds__(256) void k_gemm_scale(const float* __restrict__ A,
                                                    const float* __restrict__ W,
                                                    const float* __restrict__ dinv,
                                                    float* __restrict__ out) {
    __shared__ float w[K * M];
    for (int i = threadIdx.x; i < K * M; i += 256) w[i] = W[i];
    __syncthreads();

    constexpr int CG  = M / 4;        // col-groups per row
    constexpr int RPB = 256 / CG;     // rows per block
    int row = blockIdx.x * RPB + threadIdx.x / CG;
    int cg  = threadIdx.x % CG;
    if (row >= NN) return;

    const float* a = A + (size_t)row * K;
    float4 acc = make_float4(0.f, 0.f, 0.f, 0.f);
#pragma unroll 8
    for (int k = 0; k < K; ++k) {
        float av  = a[k];
        float4 wv = *reinterpret_cast<const float4*>(&w[k * M + cg * 4]);
        acc.x += av * wv.x;
        acc.y += av * wv.y;
        acc.z += av * wv.z;
        acc.w += av * wv.w;
    }
    float d = dinv[row];
    acc.x *= d; acc.y *= d; acc.z *= d; acc.w *= d;
    *reinterpret_cast<float4*>(&out[(size_t)row * M + cg * 4]) = acc;
}

// ---------------- agg init: agg = hs*dinv + b (self-loop term + bias) ----------------
template <int M>
__global__ void k_agg_init(const float* __restrict__ hs, const float* __restrict__ dinv,
                           const float* __restrict__ b, float* __restrict__ agg) {
    int idx = blockIdx.x * 256 + threadIdx.x;          // one float4 per thread
    constexpr int CG = M / 4;
    if (idx >= NN * CG) return;
    int row = idx / CG;
    int cg  = idx % CG;
    float d  = dinv[row];
    float4 h = *reinterpret_cast<const float4*>(&hs[(size_t)idx * 4]);
    float4 bv = *reinterpret_cast<const float4*>(&b[cg * 4]);
    float4 o;
    o.x = h.x * d + bv.x;
    o.y = h.y * d + bv.y;
    o.z = h.z * d + bv.z;
    o.w = h.w * d + bv.w;
    *reinterpret_cast<float4*>(&agg[(size_t)idx * 4]) = o;
}

// ---------------- scatter: agg[dst,:] += hs[src,:] * dinv[dst] ----------------
template <int M>
__global__ void k_scatter(const int* __restrict__ src, const int* __restrict__ dst,
                          const float* __restrict__ hs, const float* __restrict__ dinv,
                          float* __restrict__ agg) {
    constexpr int TPE = M / 4;        // threads per edge
    constexpr int EPB = 256 / TPE;    // edges per block
    int e = blockIdx.x * EPB + threadIdx.x / TPE;
    if (e >= NE) return;
    int cg = threadIdx.x % TPE;
    int s = src[e];
    int d = dst[e];
    float dv = dinv[d];
    float4 h = *reinterpret_cast<const float4*>(&hs[(size_t)s * M + cg * 4]);
    float* p = &agg[(size_t)d * M + cg * 4];
    atomicAdd(p + 0, h.x * dv);
    atomicAdd(p + 1, h.y * dv);
    atomicAdd(p + 2, h.z * dv);
    atomicAdd(p + 3, h.w * dv);
}

// ---------------- BN (eval) + ReLU ----------------
template <int M>
__global__ void k_bn_relu(const float* __restrict__ agg, const float* __restrict__ g,
                          const float* __restrict__ be, const float* __restrict__ m,
                          const float* __restrict__ v, float* __restrict__ out) {
    int idx = blockIdx.x * 256 + threadIdx.x;          // one float4 per thread
    constexpr int CG = M / 4;
    if (idx >= NN * CG) return;
    int cg = idx % CG;
    float4 a = *reinterpret_cast<const float4*>(&agg[(size_t)idx * 4]);
    float4 o;
    float* ap = &a.x;
    float* op = &o.x;
#pragma unroll
    for (int j = 0; j < 4; ++j) {
        int c = cg * 4 + j;
        float s  = g[c] * rsqrtf(v[c] + BN_EPS);
        float val = (ap[j] - m[c]) * s + be[c];
        op[j] = fmaxf(val, 0.f);
    }
    *reinterpret_cast<float4*>(&out[(size_t)idx * 4]) = o;
}

// ---------------- final: out[i] = sum_c relu(agg3[i,c]) * Wo[c] + bo ----------------
__global__ void k_final(const float* __restrict__ agg3, const float* __restrict__ Wo,
                        const float* __restrict__ bo, float* __restrict__ out) {
    int row  = blockIdx.x * 4 + (threadIdx.x >> 6);
    int lane = threadIdx.x & 63;
    if (row >= NN) return;
    float v = agg3[(size_t)row * 64 + lane];
    v = fmaxf(v, 0.f) * Wo[lane];
#pragma unroll
    for (int off = 32; off > 0; off >>= 1) v += __shfl_down(v, off, 64);
    if (lane == 0) out[row] = v + bo[0];
}

extern "C" void kernel_launch(void* const* d_in, const int* in_sizes, int n_in,
                              void* d_out, int out_size, void* d_ws, size_t ws_size,
                              hipStream_t stream) {
    const float* x   = (const float*)d_in[0];
    const int*   ei  = (const int*)d_in[1];
    const int*   src = ei;
    const int*   dst = ei + NE;
    const float* W1  = (const float*)d_in[2];
    const float* b1  = (const float*)d_in[3];
    const float* g1  = (const float*)d_in[4];
    const float* be1 = (const float*)d_in[5];
    const float* m1  = (const float*)d_in[6];
    const float* v1  = (const float*)d_in[7];
    const float* W2  = (const float*)d_in[8];
    const float* b2  = (const float*)d_in[9];
    const float* g2  = (const float*)d_in[10];
    const float* be2 = (const float*)d_in[11];
    const float* m2  = (const float*)d_in[12];
    const float* v2  = (const float*)d_in[13];
    const float* W3  = (const float*)d_in[14];
    const float* b3  = (const float*)d_in[15];
    const float* Wo  = (const float*)d_in[16];
    const float* bo  = (const float*)d_in[17];
    float* out = (float*)d_out;

    char* ws = (char*)d_ws;
    float* dinv = (float*)ws;                                // N floats (400 KB)
    float* bufA = (float*)(ws + (1 << 20));                  // 51.2 MB
    float* bufB = (float*)(ws + (1 << 20) + 51200000);       // 51.2 MB

    // degree -> dinv
    k_init_deg<<<(NN + 255) / 256, 256, 0, stream>>>(dinv);
    k_count_deg<<<(NE + 255) / 256, 256, 0, stream>>>(dst, dinv);
    k_dinv<<<(NN + 255) / 256, 256, 0, stream>>>(dinv);

    // ---- layer 1: x[N,64] @ W1[64,128] ----
    k_gemm_scale<64, 128><<<NN / 8, 256, 0, stream>>>(x, W1, dinv, bufA);      // bufA = hs1
    k_agg_init<128><<<NN * 32 / 256, 256, 0, stream>>>(bufA, dinv, b1, bufB);  // bufB = agg1
    k_scatter<128><<<NE / 8, 256, 0, stream>>>(src, dst, bufA, dinv, bufB);
    k_bn_relu<128><<<NN * 32 / 256, 256, 0, stream>>>(bufB, g1, be1, m1, v1, bufA);  // bufA = h1p

    // ---- layer 2: h1p[N,128] @ W2[128,128] ----
    k_gemm_scale<128, 128><<<NN / 8, 256, 0, stream>>>(bufA, W2, dinv, bufB);  // bufB = hs2
    k_agg_init<128><<<NN * 32 / 256, 256, 0, stream>>>(bufB, dinv, b2, bufA);  // bufA = agg2
    k_scatter<128><<<NE / 8, 256, 0, stream>>>(src, dst, bufB, dinv, bufA);
    k_bn_relu<128><<<NN * 32 / 256, 256, 0, stream>>>(bufA, g2, be2, m2, v2, bufB); // bufB = h2p

    // ---- layer 3: h2p[N,128] @ W3[128,64], relu + out dot fused ----
    k_gemm_scale<128, 64><<<NN / 16, 256, 0, stream>>>(bufB, W3, dinv, bufA);  // bufA = hs3
    k_agg_init<64><<<NN * 16 / 256, 256, 0, stream>>>(bufA, dinv, b3, bufB);   // bufB = agg3
    k_scatter<64><<<NE / 16, 256, 0, stream>>>(src, dst, bufA, dinv, bufB);
    k_final<<<(NN + 3) / 4, 256, 0, stream>>>(bufB, Wo, bo, out);
}

// Round 2
// 804.178 us; speedup vs baseline: 8.8433x; 8.8433x over previous
//
#include <hip/hip_runtime.h>

#define NN 100000
#define NE 1600000
#define NB 391          // ceil(NN/256) blocks for scan
#define BN_EPS 1e-5f

// ---------------- degree count (int) ----------------
__global__ void k_zero_int(int* __restrict__ p, int n) {
    int i = blockIdx.x * 256 + threadIdx.x;
    if (i < n) p[i] = 0;
}

__global__ void k_count_deg(const int* __restrict__ dst, int* __restrict__ deg) {
    int e = blockIdx.x * 256 + threadIdx.x;
    if (e < NE) atomicAdd(&deg[dst[e]], 1);
}

__global__ void k_dinv(const int* __restrict__ deg, float* __restrict__ dinv) {
    int i = blockIdx.x * 256 + threadIdx.x;
    if (i < NN) dinv[i] = rsqrtf((float)deg[i] + 1.0f);
}

// ---------------- hierarchical exclusive scan of deg -> offsets (in place) ----------------
__global__ __launch_bounds__(256) void k_scan_blocksums(const int* __restrict__ deg,
                                                        int* __restrict__ blk) {
    __shared__ int s[256];
    int i = blockIdx.x * 256 + threadIdx.x;
    s[threadIdx.x] = (i < NN) ? deg[i] : 0;
    __syncthreads();
    for (int off = 128; off > 0; off >>= 1) {
        if (threadIdx.x < off) s[threadIdx.x] += s[threadIdx.x + off];
        __syncthreads();
    }
    if (threadIdx.x == 0) blk[blockIdx.x] = s[0];
}

__global__ __launch_bounds__(512) void k_scan_toplevel(int* __restrict__ blk) {
    __shared__ int s[512];
    int t = threadIdx.x;
    int v = (t < NB) ? blk[t] : 0;
    s[t] = v;
    for (int off = 1; off < 512; off <<= 1) {
        __syncthreads();
        int x = (t >= off) ? s[t - off] : 0;
        __syncthreads();
        s[t] += x;
    }
    __syncthreads();
    if (t < NB) blk[t] = s[t] - v;   // exclusive
}

__global__ __launch_bounds__(256) void k_scan_final(int* __restrict__ degoff,
                                                    const int* __restrict__ blk) {
    __shared__ int s[256];
    int t = threadIdx.x;
    int i = blockIdx.x * 256 + t;
    int v = (i < NN) ? degoff[i] : 0;
    s[t] = v;
    for (int off = 1; off < 256; off <<= 1) {
        __syncthreads();
        int x = (t >= off) ? s[t - off] : 0;
        __syncthreads();
        s[t] += x;
    }
    __syncthreads();
    if (i < NN) degoff[i] = s[t] - v + blk[blockIdx.x];  // exclusive + block prefix
    if (i == 0) degoff[NN] = NE;
}

// ---------------- CSR fill ----------------
__global__ void k_csr_fill(const int* __restrict__ src, const int* __restrict__ dst,
                           const int* __restrict__ off, int* __restrict__ cur,
                           int* __restrict__ csr) {
    int e = blockIdx.x * 256 + threadIdx.x;
    if (e >= NE) return;
    int n = dst[e];
    int p = atomicAdd(&cur[n], 1);
    csr[off[n] + p] = src[e];
}

// ---------------- GEMM: out[row,:] = (A[row,:] @ W) * dinv[row] ----------------
template <int K, int M>
__global__ __launch_bounds__(256) void k_gemm_scale(const float* __restrict__ A,
                                                    const float* __restrict__ W,
                                                    const float* __restrict__ dinv,
                                                    float* __restrict__ out) {
    __shared__ float w[K * M];
    for (int i = threadIdx.x; i < K * M; i += 256) w[i] = W[i];
    __syncthreads();

    constexpr int CG  = M / 4;
    constexpr int RPB = 256 / CG;
    int row = blockIdx.x * RPB + threadIdx.x / CG;
    int cg  = threadIdx.x % CG;
    if (row >= NN) return;

    const float* a = A + (size_t)row * K;
    float4 acc = make_float4(0.f, 0.f, 0.f, 0.f);
#pragma unroll 8
    for (int k = 0; k < K; ++k) {
        float av  = a[k];
        float4 wv = *reinterpret_cast<const float4*>(&w[k * M + cg * 4]);
        acc.x += av * wv.x;
        acc.y += av * wv.y;
        acc.z += av * wv.z;
        acc.w += av * wv.w;
    }
    float d = dinv[row];
    acc.x *= d; acc.y *= d; acc.z *= d; acc.w *= d;
    *reinterpret_cast<float4*>(&out[(size_t)row * M + cg * 4]) = acc;
}

// ---------------- fused gather + self-loop + bias + BN + ReLU (M=128) ----------------
// One wave per node; lane owns cols {2*lane, 2*lane+1}.
__global__ __launch_bounds__(256) void k_gather_bn_relu128(
        const float* __restrict__ hs, const int* __restrict__ off,
        const int* __restrict__ csr, const float* __restrict__ dinv,
        const float* __restrict__ b, const float* __restrict__ g,
        const float* __restrict__ be, const float* __restrict__ m,
        const float* __restrict__ v, float* __restrict__ out) {
    int n = blockIdx.x * 4 + (threadIdx.x >> 6);
    if (n >= NN) return;
    int lane = threadIdx.x & 63;
    const float2* h2 = (const float2*)hs;

    int beg = off[n], end = off[n + 1];
    float2 a0 = make_float2(0.f, 0.f), a1 = a0, a2 = a0, a3 = a0;
    int e = beg;
    for (; e + 4 <= end; e += 4) {
        int s0 = csr[e], s1 = csr[e + 1], s2 = csr[e + 2], s3 = csr[e + 3];
        float2 v0 = h2[(size_t)s0 * 64 + lane];
        float2 v1 = h2[(size_t)s1 * 64 + lane];
        float2 v2 = h2[(size_t)s2 * 64 + lane];
        float2 v3 = h2[(size_t)s3 * 64 + lane];
        a0.x += v0.x; a0.y += v0.y;
        a1.x += v1.x; a1.y += v1.y;
        a2.x += v2.x; a2.y += v2.y;
        a3.x += v3.x; a3.y += v3.y;
    }
    for (; e < end; ++e) {
        float2 v0 = h2[(size_t)csr[e] * 64 + lane];
        a0.x += v0.x; a0.y += v0.y;
    }
    float2 self = h2[(size_t)n * 64 + lane];
    float d = dinv[n];
    float sx = (a0.x + a1.x + a2.x + a3.x + self.x) * d;
    float sy = (a0.y + a1.y + a2.y + a3.y + self.y) * d;

    int c0 = lane * 2, c1 = c0 + 1;
    sx += b[c0]; sy += b[c1];
    float sc0 = g[c0] * rsqrtf(v[c0] + BN_EPS);
    float sc1 = g[c1] * rsqrtf(v[c1] + BN_EPS);
    float2 o;
    o.x = fmaxf((sx - m[c0]) * sc0 + be[c0], 0.f);
    o.y = fmaxf((sy - m[c1]) * sc1 + be[c1], 0.f);
    ((float2*)out)[(size_t)n * 64 + lane] = o;
}

// ---------------- fused gather + self + bias + ReLU + (·Wo + bo) (M=64) ----------------
// One wave per node; lane owns col lane; wave-reduce the final dot.
__global__ __launch_bounds__(256) void k_gather_final64(
        const float* __restrict__ hs, const int* __restrict__ off,
        const int* __restrict__ csr, const float* __restrict__ dinv,
        const float* __restrict__ b, const float* __restrict__ Wo,
        const float* __restrict__ bo, float* __restrict__ out) {
    int n = blockIdx.x * 4 + (threadIdx.x >> 6);
    if (n >= NN) return;
    int lane = threadIdx.x & 63;

    int beg = off[n], end = off[n + 1];
    float a0 = 0.f, a1 = 0.f, a2 = 0.f, a3 = 0.f;
    int e = beg;
    for (; e + 4 <= end; e += 4) {
        int s0 = csr[e], s1 = csr[e + 1], s2 = csr[e + 2], s3 = csr[e + 3];
        a0 += hs[(size_t)s0 * 64 + lane];
        a1 += hs[(size_t)s1 * 64 + lane];
        a2 += hs[(size_t)s2 * 64 + lane];
        a3 += hs[(size_t)s3 * 64 + lane];
    }
    for (; e < end; ++e) a0 += hs[(size_t)csr[e] * 64 + lane];

    float val = (a0 + a1 + a2 + a3 + hs[(size_t)n * 64 + lane]) * dinv[n] + b[lane];
    val = fmaxf(val, 0.f) * Wo[lane];
#pragma unroll
    for (int o = 32; o > 0; o >>= 1) val += __shfl_down(val, o, 64);
    if (lane == 0) out[n] = val + bo[0];
}

extern "C" void kernel_launch(void* const* d_in, const int* in_sizes, int n_in,
                              void* d_out, int out_size, void* d_ws, size_t ws_size,
                              hipStream_t stream) {
    const float* x   = (const float*)d_in[0];
    const int*   ei  = (const int*)d_in[1];
    const int*   src = ei;
    const int*   dst = ei + NE;
    const float* W1  = (const float*)d_in[2];
    const float* b1  = (const float*)d_in[3];
    const float* g1  = (const float*)d_in[4];
    const float* be1 = (const float*)d_in[5];
    const float* m1  = (const float*)d_in[6];
    const float* v1  = (const float*)d_in[7];
    const float* W2  = (const float*)d_in[8];
    const float* b2  = (const float*)d_in[9];
    const float* g2  = (const float*)d_in[10];
    const float* be2 = (const float*)d_in[11];
    const float* m2  = (const float*)d_in[12];
    const float* v2  = (const float*)d_in[13];
    const float* W3  = (const float*)d_in[14];
    const float* b3  = (const float*)d_in[15];
    const float* Wo  = (const float*)d_in[16];
    const float* bo  = (const float*)d_in[17];
    float* out = (float*)d_out;

    char* ws = (char*)d_ws;
    float* dinv   = (float*)(ws + 0);            // 400,000 B
    int*   degoff = (int*)(ws + 400000);         // (N+1) ints, scanned in place
    int*   cur    = (int*)(ws + 800032);         // 400,000 B
    int*   blk    = (int*)(ws + 1200032);        // NB ints
    int*   csr    = (int*)(ws + 1201600);        // 6,400,000 B
    float* bufA   = (float*)(ws + 7601600);      // 51,200,000 B
    float* bufB   = (float*)(ws + 58801600);     // 51,200,000 B  (end ~110 MB)

    int gN = (NN + 255) / 256;
    int gE = (NE + 255) / 256;
    int gW = (NN + 3) / 4;       // wave-per-node kernels (4 waves/block)

    // ---- CSR build ----
    k_zero_int<<<gN, 256, 0, stream>>>(degoff, NN);
    k_zero_int<<<gN, 256, 0, stream>>>(cur, NN);
    k_count_deg<<<gE, 256, 0, stream>>>(dst, degoff);
    k_dinv<<<gN, 256, 0, stream>>>(degoff, dinv);
    k_scan_blocksums<<<NB, 256, 0, stream>>>(degoff, blk);
    k_scan_toplevel<<<1, 512, 0, stream>>>(blk);
    k_scan_final<<<NB, 256, 0, stream>>>(degoff, blk);
    k_csr_fill<<<gE, 256, 0, stream>>>(src, dst, degoff, cur, csr);

    // ---- layer 1: x[N,64] @ W1[64,128] ----
    k_gemm_scale<64, 128><<<NN / 8, 256, 0, stream>>>(x, W1, dinv, bufA);
    k_gather_bn_relu128<<<gW, 256, 0, stream>>>(bufA, degoff, csr, dinv,
                                                b1, g1, be1, m1, v1, bufB);

    // ---- layer 2: h1'[N,128] @ W2[128,128] ----
    k_gemm_scale<128, 128><<<NN / 8, 256, 0, stream>>>(bufB, W2, dinv, bufA);
    k_gather_bn_relu128<<<gW, 256, 0, stream>>>(bufA, degoff, csr, dinv,
                                                b2, g2, be2, m2, v2, bufB);

    // ---- layer 3: h2'[N,128] @ W3[128,64] + fused final ----
    k_gemm_scale<128, 64><<<NN / 16, 256, 0, stream>>>(bufB, W3, dinv, bufA);
    k_gather_final64<<<gW, 256, 0, stream>>>(bufA, degoff, csr, dinv,
                                             b3, Wo, bo, out);
}

// Round 3
// 693.798 us; speedup vs baseline: 10.2502x; 1.1591x over previous
//
#include <hip/hip_runtime.h>

#define NN 100000
#define NE 1600000
#define NB 391          // ceil(NN/256) blocks for scan
#define BN_EPS 1e-5f

// ---------------- degree count (int) ----------------
__global__ void k_zero_int(int* __restrict__ p, int n) {
    int i = blockIdx.x * 256 + threadIdx.x;
    if (i < n) p[i] = 0;
}

__global__ void k_count_deg(const int* __restrict__ dst, int* __restrict__ deg) {
    int e = blockIdx.x * 256 + threadIdx.x;
    if (e < NE) atomicAdd(&deg[dst[e]], 1);
}

__global__ void k_dinv(const int* __restrict__ deg, float* __restrict__ dinv) {
    int i = blockIdx.x * 256 + threadIdx.x;
    if (i < NN) dinv[i] = rsqrtf((float)deg[i] + 1.0f);
}

// ---------------- hierarchical exclusive scan of deg -> offsets (in place) ----------------
__global__ __launch_bounds__(256) void k_scan_blocksums(const int* __restrict__ deg,
                                                        int* __restrict__ blk) {
    __shared__ int s[256];
    int i = blockIdx.x * 256 + threadIdx.x;
    s[threadIdx.x] = (i < NN) ? deg[i] : 0;
    __syncthreads();
    for (int off = 128; off > 0; off >>= 1) {
        if (threadIdx.x < off) s[threadIdx.x] += s[threadIdx.x + off];
        __syncthreads();
    }
    if (threadIdx.x == 0) blk[blockIdx.x] = s[0];
}

__global__ __launch_bounds__(512) void k_scan_toplevel(int* __restrict__ blk) {
    __shared__ int s[512];
    int t = threadIdx.x;
    int v = (t < NB) ? blk[t] : 0;
    s[t] = v;
    for (int off = 1; off < 512; off <<= 1) {
        __syncthreads();
        int x = (t >= off) ? s[t - off] : 0;
        __syncthreads();
        s[t] += x;
    }
    __syncthreads();
    if (t < NB) blk[t] = s[t] - v;   // exclusive
}

__global__ __launch_bounds__(256) void k_scan_final(int* __restrict__ degoff,
                                                    const int* __restrict__ blk) {
    __shared__ int s[256];
    int t = threadIdx.x;
    int i = blockIdx.x * 256 + t;
    int v = (i < NN) ? degoff[i] : 0;
    s[t] = v;
    for (int off = 1; off < 256; off <<= 1) {
        __syncthreads();
        int x = (t >= off) ? s[t - off] : 0;
        __syncthreads();
        s[t] += x;
    }
    __syncthreads();
    if (i < NN) degoff[i] = s[t] - v + blk[blockIdx.x];  // exclusive + block prefix
    if (i == 0) degoff[NN] = NE;
}

// ---------------- CSR fill ----------------
__global__ void k_csr_fill(const int* __restrict__ src, const int* __restrict__ dst,
                           const int* __restrict__ off, int* __restrict__ cur,
                           int* __restrict__ csr) {
    int e = blockIdx.x * 256 + threadIdx.x;
    if (e >= NE) return;
    int n = dst[e];
    int p = atomicAdd(&cur[n], 1);
    csr[off[n] + p] = src[e];
}

// ---------------- GEMM: out[row,:] = (A[row,:] @ W) * dinv[row] ----------------
// Register-tiled: each thread computes 4 rows x 4 cols. W fully LDS-staged.
// Per k4-step: 4 global float4 A loads (lane-broadcast) + 4 LDS float4 W loads
// feed 64 FMAs.
template <int K, int M>
__global__ __launch_bounds__(256) void k_gemm_scale(const float* __restrict__ A,
                                                    const float* __restrict__ W,
                                                    const float* __restrict__ dinv,
                                                    float* __restrict__ out) {
    constexpr int CG   = M / 4;         // col-groups (float4 cols)
    constexpr int RG   = 256 / CG;      // row-groups per block
    constexpr int ROWS = RG * 4;        // rows per block
    constexpr int K4   = K / 4;

    __shared__ float w[K * M];
    for (int i = threadIdx.x; i < K * M / 4; i += 256)
        ((float4*)w)[i] = ((const float4*)W)[i];
    __syncthreads();

    int cg   = threadIdx.x % CG;
    int rg   = threadIdx.x / CG;
    int row0 = blockIdx.x * ROWS + rg * 4;

    const float4* A4 = (const float4*)A;
    const float4* w4 = (const float4*)w;

    const float4* ap[4];
#pragma unroll
    for (int j = 0; j < 4; ++j) {
        int r = row0 + j;
        if (r >= NN) r = NN - 1;
        ap[j] = A4 + (size_t)r * K4;
    }

    float4 acc[4];
#pragma unroll
    for (int j = 0; j < 4; ++j) acc[j] = make_float4(0.f, 0.f, 0.f, 0.f);

#pragma unroll 4
    for (int k4 = 0; k4 < K4; ++k4) {
        float4 a0 = ap[0][k4];
        float4 a1 = ap[1][k4];
        float4 a2 = ap[2][k4];
        float4 a3 = ap[3][k4];
        float4 w0 = w4[(k4 * 4 + 0) * CG + cg];
        float4 w1 = w4[(k4 * 4 + 1) * CG + cg];
        float4 w2 = w4[(k4 * 4 + 2) * CG + cg];
        float4 w3 = w4[(k4 * 4 + 3) * CG + cg];
#define FMA4(ACC, AV)                                                     \
        ACC.x += AV.x * w0.x + AV.y * w1.x + AV.z * w2.x + AV.w * w3.x;   \
        ACC.y += AV.x * w0.y + AV.y * w1.y + AV.z * w2.y + AV.w * w3.y;   \
        ACC.z += AV.x * w0.z + AV.y * w1.z + AV.z * w2.z + AV.w * w3.z;   \
        ACC.w += AV.x * w0.w + AV.y * w1.w + AV.z * w2.w + AV.w * w3.w;
        FMA4(acc[0], a0)
        FMA4(acc[1], a1)
        FMA4(acc[2], a2)
        FMA4(acc[3], a3)
#undef FMA4
    }

#pragma unroll
    for (int j = 0; j < 4; ++j) {
        int r = row0 + j;
        if (r < NN) {
            float d = dinv[r];
            float4 o = acc[j];
            o.x *= d; o.y *= d; o.z *= d; o.w *= d;
            ((float4*)out)[(size_t)r * CG + cg] = o;
        }
    }
}

// ---------------- fused gather + self-loop + bias + BN + ReLU (M=128) ----------------
// One wave per node; lane owns cols {2*lane, 2*lane+1}.
__global__ __launch_bounds__(256) void k_gather_bn_relu128(
        const float* __restrict__ hs, const int* __restrict__ off,
        const int* __restrict__ csr, const float* __restrict__ dinv,
        const float* __restrict__ b, const float* __restrict__ g,
        const float* __restrict__ be, const float* __restrict__ m,
        const float* __restrict__ v, float* __restrict__ out) {
    int n = blockIdx.x * 4 + (threadIdx.x >> 6);
    if (n >= NN) return;
    int lane = threadIdx.x & 63;
    const float2* h2 = (const float2*)hs;

    int beg = off[n], end = off[n + 1];
    float2 a0 = make_float2(0.f, 0.f), a1 = a0, a2 = a0, a3 = a0;
    int e = beg;
    for (; e + 4 <= end; e += 4) {
        int s0 = csr[e], s1 = csr[e + 1], s2 = csr[e + 2], s3 = csr[e + 3];
        float2 v0 = h2[(size_t)s0 * 64 + lane];
        float2 v1 = h2[(size_t)s1 * 64 + lane];
        float2 v2 = h2[(size_t)s2 * 64 + lane];
        float2 v3 = h2[(size_t)s3 * 64 + lane];
        a0.x += v0.x; a0.y += v0.y;
        a1.x += v1.x; a1.y += v1.y;
        a2.x += v2.x; a2.y += v2.y;
        a3.x += v3.x; a3.y += v3.y;
    }
    for (; e < end; ++e) {
        float2 v0 = h2[(size_t)csr[e] * 64 + lane];
        a0.x += v0.x; a0.y += v0.y;
    }
    float2 self = h2[(size_t)n * 64 + lane];
    float d = dinv[n];
    float sx = (a0.x + a1.x + a2.x + a3.x + self.x) * d;
    float sy = (a0.y + a1.y + a2.y + a3.y + self.y) * d;

    int c0 = lane * 2, c1 = c0 + 1;
    sx += b[c0]; sy += b[c1];
    float sc0 = g[c0] * rsqrtf(v[c0] + BN_EPS);
    float sc1 = g[c1] * rsqrtf(v[c1] + BN_EPS);
    float2 o;
    o.x = fmaxf((sx - m[c0]) * sc0 + be[c0], 0.f);
    o.y = fmaxf((sy - m[c1]) * sc1 + be[c1], 0.f);
    ((float2*)out)[(size_t)n * 64 + lane] = o;
}

// ---------------- fused gather + self + bias + ReLU + (·Wo + bo) (M=64) ----------------
__global__ __launch_bounds__(256) void k_gather_final64(
        const float* __restrict__ hs, const int* __restrict__ off,
        const int* __restrict__ csr, const float* __restrict__ dinv,
        const float* __restrict__ b, const float* __restrict__ Wo,
        const float* __restrict__ bo, float* __restrict__ out) {
    int n = blockIdx.x * 4 + (threadIdx.x >> 6);
    if (n >= NN) return;
    int lane = threadIdx.x & 63;

    int beg = off[n], end = off[n + 1];
    float a0 = 0.f, a1 = 0.f, a2 = 0.f, a3 = 0.f;
    int e = beg;
    for (; e + 4 <= end; e += 4) {
        int s0 = csr[e], s1 = csr[e + 1], s2 = csr[e + 2], s3 = csr[e + 3];
        a0 += hs[(size_t)s0 * 64 + lane];
        a1 += hs[(size_t)s1 * 64 + lane];
        a2 += hs[(size_t)s2 * 64 + lane];
        a3 += hs[(size_t)s3 * 64 + lane];
    }
    for (; e < end; ++e) a0 += hs[(size_t)csr[e] * 64 + lane];

    float val = (a0 + a1 + a2 + a3 + hs[(size_t)n * 64 + lane]) * dinv[n] + b[lane];
    val = fmaxf(val, 0.f) * Wo[lane];
#pragma unroll
    for (int o = 32; o > 0; o >>= 1) val += __shfl_down(val, o, 64);
    if (lane == 0) out[n] = val + bo[0];
}

extern "C" void kernel_launch(void* const* d_in, const int* in_sizes, int n_in,
                              void* d_out, int out_size, void* d_ws, size_t ws_size,
                              hipStream_t stream) {
    const float* x   = (const float*)d_in[0];
    const int*   ei  = (const int*)d_in[1];
    const int*   src = ei;
    const int*   dst = ei + NE;
    const float* W1  = (const float*)d_in[2];
    const float* b1  = (const float*)d_in[3];
    const float* g1  = (const float*)d_in[4];
    const float* be1 = (const float*)d_in[5];
    const float* m1  = (const float*)d_in[6];
    const float* v1  = (const float*)d_in[7];
    const float* W2  = (const float*)d_in[8];
    const float* b2  = (const float*)d_in[9];
    const float* g2  = (const float*)d_in[10];
    const float* be2 = (const float*)d_in[11];
    const float* m2  = (const float*)d_in[12];
    const float* v2  = (const float*)d_in[13];
    const float* W3  = (const float*)d_in[14];
    const float* b3  = (const float*)d_in[15];
    const float* Wo  = (const float*)d_in[16];
    const float* bo  = (const float*)d_in[17];
    float* out = (float*)d_out;

    char* ws = (char*)d_ws;
    float* dinv   = (float*)(ws + 0);            // 400,000 B
    int*   degoff = (int*)(ws + 400000);         // (N+1) ints, scanned in place
    int*   cur    = (int*)(ws + 800032);         // 400,000 B
    int*   blk    = (int*)(ws + 1200032);        // NB ints
    int*   csr    = (int*)(ws + 1201600);        // 6,400,000 B
    float* bufA   = (float*)(ws + 7601600);      // 51,200,000 B
    float* bufB   = (float*)(ws + 58801600);     // 51,200,000 B  (end ~110 MB)

    int gN = (NN + 255) / 256;
    int gE = (NE + 255) / 256;
    int gW = (NN + 3) / 4;       // wave-per-node kernels (4 waves/block)

    // ---- CSR build ----
    k_zero_int<<<gN, 256, 0, stream>>>(degoff, NN);
    k_zero_int<<<gN, 256, 0, stream>>>(cur, NN);
    k_count_deg<<<gE, 256, 0, stream>>>(dst, degoff);
    k_dinv<<<gN, 256, 0, stream>>>(degoff, dinv);
    k_scan_blocksums<<<NB, 256, 0, stream>>>(degoff, blk);
    k_scan_toplevel<<<1, 512, 0, stream>>>(blk);
    k_scan_final<<<NB, 256, 0, stream>>>(degoff, blk);
    k_csr_fill<<<gE, 256, 0, stream>>>(src, dst, degoff, cur, csr);

    // ---- layer 1: x[N,64] @ W1[64,128] ----   32 rows/block
    k_gemm_scale<64, 128><<<(NN + 31) / 32, 256, 0, stream>>>(x, W1, dinv, bufA);
    k_gather_bn_relu128<<<gW, 256, 0, stream>>>(bufA, degoff, csr, dinv,
                                                b1, g1, be1, m1, v1, bufB);

    // ---- layer 2: h1'[N,128] @ W2[128,128] ----   32 rows/block
    k_gemm_scale<128, 128><<<(NN + 31) / 32, 256, 0, stream>>>(bufB, W2, dinv, bufA);
    k_gather_bn_relu128<<<gW, 256, 0, stream>>>(bufA, degoff, csr, dinv,
                                                b2, g2, be2, m2, v2, bufB);

    // ---- layer 3: h2'[N,128] @ W3[128,64] + fused final ----   64 rows/block
    k_gemm_scale<128, 64><<<(NN + 63) / 64, 256, 0, stream>>>(bufB, W3, dinv, bufA);
    k_gather_final64<<<gW, 256, 0, stream>>>(bufA, degoff, csr, dinv,
                                             b3, Wo, bo, out);
}